// Round 1
// baseline (494.175 us; speedup 1.0000x reference)
//
#include <hip/hip_runtime.h>
#include <hip/hip_bf16.h>
#include <stdint.h>

// Problem constants (fixed by the reference setup_inputs)
#define BATCH 128
#define SEQN  384
#define SEQM  384
#define DIM   128
#define KINF  1000000.0f   // reference pseudo-infinity

typedef __attribute__((ext_vector_type(8))) short bf16x8;   // 8 bf16 = 4 VGPRs (MFMA A/B frag)
typedef __attribute__((ext_vector_type(4))) float f32x4;    // MFMA C/D frag

__device__ __forceinline__ short bf16_trunc(float x) {
    // bit-truncate fp32 -> bf16 (error <= 2^-8 rel; absmax threshold is ~1966, fine)
    return (short)(__float_as_uint(x) >> 16);
}

__device__ __forceinline__ bf16x8 load_cvt8(const float* __restrict__ p) {
    float4 lo = *(const float4*)p;
    float4 hi = *(const float4*)(p + 4);
    bf16x8 r;
    r[0] = bf16_trunc(lo.x); r[1] = bf16_trunc(lo.y);
    r[2] = bf16_trunc(lo.z); r[3] = bf16_trunc(lo.w);
    r[4] = bf16_trunc(hi.x); r[5] = bf16_trunc(hi.y);
    r[6] = bf16_trunc(hi.z); r[7] = bf16_trunc(hi.w);
    return r;
}

// ---------------------------------------------------------------------------
// Kernel 1: row norms.  One wave per row (128 floats -> float2 per lane),
// shuffle-reduce across the 64-lane wave.  rows 0..B*N-1 -> a, rest -> b.
// ---------------------------------------------------------------------------
__global__ __launch_bounds__(256) void norms_kernel(
        const float* __restrict__ a, const float* __restrict__ b,
        float* __restrict__ anorm, float* __restrict__ bnorm) {
    int wave = threadIdx.x >> 6;
    int lane = threadIdx.x & 63;
    long row = (long)blockIdx.x * 4 + wave;          // 0 .. 98303
    const long total = (long)BATCH * SEQN;           // 49152
    const float* src; float* dst; long r;
    if (row < total) { src = a; dst = anorm; r = row; }
    else             { src = b; dst = bnorm; r = row - total; }
    const float2* p = (const float2*)(src + r * DIM);
    float2 v = p[lane];
    float s = v.x * v.x + v.y * v.y;
    #pragma unroll
    for (int off = 32; off > 0; off >>= 1) s += __shfl_down(s, off, 64);
    if (lane == 0) dst[r] = s;
}

// ---------------------------------------------------------------------------
// Kernel 2: batched D = anorm[i] + bnorm[j] - 2 * a.b via bf16 MFMA.
// Block = 256 thr (4 waves), 64x64 tile per block; wave = 32x32 (2x2 of
// 16x16x32 subtiles).  a,b are [row][k] row-major -> both A and B fragments
// load 8 contiguous k-elems from row (lane&15), k-offset (lane>>4)*8.
// C/D layout: col = lane&15 (j), row = (lane>>4)*4 + reg (i).
// ---------------------------------------------------------------------------
__global__ __launch_bounds__(256) void gemm_kernel(
        const float* __restrict__ a, const float* __restrict__ b,
        const float* __restrict__ anorm, const float* __restrict__ bnorm,
        float* __restrict__ Dmat) {
    const int batch = blockIdx.z;
    const int it = blockIdx.y, jt = blockIdx.x;
    const int wave = threadIdx.x >> 6, lane = threadIdx.x & 63;
    const int wi = wave >> 1, wj = wave & 1;
    const int i0 = it * 64 + wi * 32;
    const int j0 = jt * 64 + wj * 32;
    const int l16 = lane & 15, quad = lane >> 4;

    const float* abase = a + ((long)batch * SEQN + i0 + l16) * DIM + quad * 8;
    const float* bbase = b + ((long)batch * SEQM + j0 + l16) * DIM + quad * 8;

    f32x4 acc[2][2] = {};
    #pragma unroll
    for (int kk = 0; kk < 4; kk++) {                 // K = 4 * 32
        bf16x8 af[2], bfr[2];
        #pragma unroll
        for (int s = 0; s < 2; s++) {
            af[s]  = load_cvt8(abase + (long)s * 16 * DIM + kk * 32);
            bfr[s] = load_cvt8(bbase + (long)s * 16 * DIM + kk * 32);
        }
        #pragma unroll
        for (int si = 0; si < 2; si++)
            #pragma unroll
            for (int sj = 0; sj < 2; sj++)
                acc[si][sj] = __builtin_amdgcn_mfma_f32_16x16x32_bf16(
                                  af[si], bfr[sj], acc[si][sj], 0, 0, 0);
    }

    #pragma unroll
    for (int si = 0; si < 2; si++) {
        #pragma unroll
        for (int sj = 0; sj < 2; sj++) {
            int j = j0 + sj * 16 + l16;
            float bn = bnorm[(long)batch * SEQM + j];
            #pragma unroll
            for (int r = 0; r < 4; r++) {
                int i = i0 + si * 16 + quad * 4 + r;
                float v = anorm[(long)batch * SEQN + i] + bn - 2.0f * acc[si][sj][r];
                Dmat[((long)batch * SEQN + i) * SEQM + j] = v;
            }
        }
    }
}

// ---------------------------------------------------------------------------
// Kernel 3: soft-DTW DP, one block per batch, anti-diagonal wavefront.
// buf[t%3][i] = R[i, t-i].  Thread tid owns i = tid+1 and sweeps D row i-1
// sequentially (float4-buffered).  767 barrier steps.
// ---------------------------------------------------------------------------
__global__ __launch_bounds__(384) void dtw_kernel(
        const float* __restrict__ Dmat, float* __restrict__ out) {
    __shared__ float buf[3][SEQN + 1];               // 3 * 385 * 4 B
    const int b   = blockIdx.x;
    const int tid = threadIdx.x;                     // 0..383
    const int i   = tid + 1;                         // 1..384
    const float* drow = Dmat + ((long)b * SEQN + (i - 1)) * SEQM;

    // t = 0: R[0,0] = 0;  t = 1: all INF
    if (tid == 0) { buf[0][0] = 0.0f; buf[1][0] = KINF; }
    buf[0][i] = KINF;
    buf[1][i] = KINF;
    __syncthreads();

    float4 dq = make_float4(0.f, 0.f, 0.f, 0.f);
    float  v  = KINF;
    for (int t = 2; t <= SEQN + SEQM; t++) {
        float*       cur = buf[t % 3];
        const float* tm1 = buf[(t + 2) % 3];
        const float* tm2 = buf[(t + 1) % 3];
        int j = t - i;
        v = KINF;
        if (j >= 1 && j <= SEQM) {
            int c = j - 1;
            if ((c & 3) == 0) dq = *(const float4*)(drow + c);
            float d  = (c & 2) ? ((c & 1) ? dq.w : dq.z) : ((c & 1) ? dq.y : dq.x);
            float rd = tm2[i - 1];                   // R[i-1, j-1]
            float ru = tm1[i - 1];                   // R[i-1, j]
            float rl = tm1[i];                       // R[i, j-1]
            float m  = fminf(rd, fminf(ru, rl));
            float s  = __expf(m - rd) + __expf(m - ru) + __expf(m - rl);
            v = d + m - __logf(s);
        }
        cur[i] = v;
        if (tid == 0) cur[0] = KINF;
        __syncthreads();
    }
    // R[N, M] is diagonal t = N+M at i = N -> thread tid = N-1
    if (tid == SEQN - 1) out[b] = v;
}

// ---------------------------------------------------------------------------
extern "C" void kernel_launch(void* const* d_in, const int* in_sizes, int n_in,
                              void* d_out, int out_size, void* d_ws, size_t ws_size,
                              hipStream_t stream) {
    (void)in_sizes; (void)n_in; (void)out_size; (void)ws_size;
    const float* a = (const float*)d_in[0];
    const float* b = (const float*)d_in[1];
    float* out = (float*)d_out;

    // workspace layout (all fp32): anorm | bnorm | D   -> 75,890,688 bytes
    float* anorm = (float*)d_ws;
    float* bnorm = anorm + (long)BATCH * SEQN;
    float* Dmat  = bnorm + (long)BATCH * SEQM;

    // 98304 rows total, 4 rows (waves) per 256-thread block
    norms_kernel<<<dim3((BATCH * (SEQN + SEQM) * 2) / 8 / 4 * 4 / 256 ? 24576 : 24576),
                   dim3(256), 0, stream>>>(a, b, anorm, bnorm);
    gemm_kernel<<<dim3(SEQM / 64, SEQN / 64, BATCH), dim3(256), 0, stream>>>(
        a, b, anorm, bnorm, Dmat);
    dtw_kernel<<<dim3(BATCH), dim3(SEQN), 0, stream>>>(Dmat, out);
}

// Round 3
// 427.215 us; speedup vs baseline: 1.1567x; 1.1567x over previous
//
#include <hip/hip_runtime.h>
#include <hip/hip_bf16.h>
#include <stdint.h>

// Problem constants (fixed by the reference setup_inputs)
#define BATCH 128
#define SEQN  384
#define SEQM  384
#define DIM   128
#define KINF   1000000.0f                 // reference pseudo-infinity (nat units)
#define LOG2E  1.4426950408889634f
#define LN2    0.6931471805599453f
#define KINF2  (KINF * LOG2E)             // pseudo-infinity in base-2-scaled units
#define TROWS  6                          // rows per lane in the DP (64*6 = 384)

// hardware base-2 transcendentals (v_exp_f32 / v_log_f32)
#define EXP2F(x) __builtin_amdgcn_exp2f(x)
#define LOG2F(x) __builtin_amdgcn_logf(x)

typedef __attribute__((ext_vector_type(8))) short bf16x8;   // 8 bf16 = 4 VGPRs (MFMA A/B frag)
typedef __attribute__((ext_vector_type(4))) float f32x4;    // MFMA C/D frag

__device__ __forceinline__ short bf16_rne(float x) {
    // round-to-nearest-even fp32 -> bf16 (less bias than truncation)
    uint32_t u = __float_as_uint(x);
    u += 0x7FFFu + ((u >> 16) & 1u);
    return (short)(u >> 16);
}

__device__ __forceinline__ bf16x8 load_cvt8(const float* __restrict__ p) {
    float4 lo = *(const float4*)p;
    float4 hi = *(const float4*)(p + 4);
    bf16x8 r;
    r[0] = bf16_rne(lo.x); r[1] = bf16_rne(lo.y);
    r[2] = bf16_rne(lo.z); r[3] = bf16_rne(lo.w);
    r[4] = bf16_rne(hi.x); r[5] = bf16_rne(hi.y);
    r[6] = bf16_rne(hi.z); r[7] = bf16_rne(hi.w);
    return r;
}

// ---------------------------------------------------------------------------
// Kernel 1: row norms.  One wave per row (128 floats -> float2 per lane),
// shuffle-reduce across the 64-lane wave.  rows 0..B*N-1 -> a, rest -> b.
// ---------------------------------------------------------------------------
__global__ __launch_bounds__(256) void norms_kernel(
        const float* __restrict__ a, const float* __restrict__ b,
        float* __restrict__ anorm, float* __restrict__ bnorm) {
    int wave = threadIdx.x >> 6;
    int lane = threadIdx.x & 63;
    long row = (long)blockIdx.x * 4 + wave;          // 0 .. 98303
    const long total = (long)BATCH * SEQN;           // 49152
    const float* src; float* dst; long r;
    if (row < total) { src = a; dst = anorm; r = row; }
    else             { src = b; dst = bnorm; r = row - total; }
    const float2* p = (const float2*)(src + r * DIM);
    float2 v = p[lane];
    float s = v.x * v.x + v.y * v.y;
    #pragma unroll
    for (int off = 32; off > 0; off >>= 1) s += __shfl_down(s, off, 64);
    if (lane == 0) dst[r] = s;
}

// ---------------------------------------------------------------------------
// Kernel 2: batched D = (anorm[i] + bnorm[j] - 2 * a.b) * LOG2E via bf16 MFMA.
// D is pre-scaled by log2(e) so the DP can use v_exp_f32/v_log_f32 (base-2)
// with no per-step scale multiplies.
// ---------------------------------------------------------------------------
__global__ __launch_bounds__(256) void gemm_kernel(
        const float* __restrict__ a, const float* __restrict__ b,
        const float* __restrict__ anorm, const float* __restrict__ bnorm,
        float* __restrict__ Dmat) {
    const int batch = blockIdx.z;
    const int it = blockIdx.y, jt = blockIdx.x;
    const int wave = threadIdx.x >> 6, lane = threadIdx.x & 63;
    const int wi = wave >> 1, wj = wave & 1;
    const int i0 = it * 64 + wi * 32;
    const int j0 = jt * 64 + wj * 32;
    const int l16 = lane & 15, quad = lane >> 4;

    const float* abase = a + ((long)batch * SEQN + i0 + l16) * DIM + quad * 8;
    const float* bbase = b + ((long)batch * SEQM + j0 + l16) * DIM + quad * 8;

    f32x4 acc[2][2] = {};
    #pragma unroll
    for (int kk = 0; kk < 4; kk++) {                 // K = 4 * 32
        bf16x8 af[2], bfr[2];
        #pragma unroll
        for (int s = 0; s < 2; s++) {
            af[s]  = load_cvt8(abase + (long)s * 16 * DIM + kk * 32);
            bfr[s] = load_cvt8(bbase + (long)s * 16 * DIM + kk * 32);
        }
        #pragma unroll
        for (int si = 0; si < 2; si++)
            #pragma unroll
            for (int sj = 0; sj < 2; sj++)
                acc[si][sj] = __builtin_amdgcn_mfma_f32_16x16x32_bf16(
                                  af[si], bfr[sj], acc[si][sj], 0, 0, 0);
    }

    #pragma unroll
    for (int si = 0; si < 2; si++) {
        #pragma unroll
        for (int sj = 0; sj < 2; sj++) {
            int j = j0 + sj * 16 + l16;
            float bn = bnorm[(long)batch * SEQM + j];
            #pragma unroll
            for (int r = 0; r < 4; r++) {
                int i = i0 + si * 16 + quad * 4 + r;
                float v = (anorm[(long)batch * SEQN + i] + bn - 2.0f * acc[si][sj][r]) * LOG2E;
                Dmat[((long)batch * SEQN + i) * SEQM + j] = v;
            }
        }
    }
}

// ---------------------------------------------------------------------------
// Kernel 3: soft-DTW DP.  ONE WAVE per batch, no LDS, no __syncthreads.
// Lane t owns rows i = 6t+1 .. 6t+6 (1-based).  At step s, lane t computes
// column j = s - t for its 6 rows as a pure register chain.  The band's
// bottom-row value moves to lane t+1 via __shfl_up each step:
//   up_cur  (set end of step s-1) = R[6t][j]      (lane t-1's bottom, col j)
//   up_diag (set end of step s-2) = R[6t][j-1]
// D is consumed via double-buffered float4 per row (prefetch 4 columns
// ahead) so global-load latency is off the critical path.
// All values carry a log2(e) scale (D pre-scaled); output unscales by ln2.
// ---------------------------------------------------------------------------
__global__ __launch_bounds__(64) void dtw_kernel(
        const float* __restrict__ Dmat, float* __restrict__ out) {
    const int b = blockIdx.x;
    const int t = threadIdx.x;                       // lane 0..63
    const float* __restrict__ dbase = Dmat + ((long)b * SEQN + t * TROWS) * SEQM;

    float prev[TROWS];                               // R[row][j-1] for own rows
    #pragma unroll
    for (int r = 0; r < TROWS; r++) prev[r] = KINF2;

    float4 cur[TROWS], nxt[TROWS];
    #pragma unroll
    for (int r = 0; r < TROWS; r++)                  // prefetch cols 0..3
        nxt[r] = *(const float4*)(dbase + r * SEQM);

    float bottom  = KINF2;                           // own row 6t+6, last computed col
    float up_cur  = KINF2;                           // lane0: R[0][1] = INF
    float up_diag = (t == 0) ? 0.0f : KINF2;         // lane0: R[0][0] = 0

    for (int s = 1; s <= SEQM + 63; s++) {           // 447 steps
        int j = s - t;
        if (j >= 1 && j <= SEQM) {
            int c = j - 1;
            if ((c & 3) == 0) {
                #pragma unroll
                for (int r = 0; r < TROWS; r++) cur[r] = nxt[r];
                int cn = c + 4; if (cn > SEQM - 4) cn = SEQM - 4;
                #pragma unroll
                for (int r = 0; r < TROWS; r++)
                    nxt[r] = *(const float4*)(dbase + r * SEQM + cn);
            }
            float up = up_cur, diag = up_diag;
            #pragma unroll
            for (int r = 0; r < TROWS; r++) {
                float d = (c & 2) ? ((c & 1) ? cur[r].w : cur[r].z)
                                  : ((c & 1) ? cur[r].y : cur[r].x);
                float left = prev[r];
                float m  = fminf(diag, fminf(up, left));   // v_min3_f32
                float ss = EXP2F(m - diag) + EXP2F(m - up) + EXP2F(m - left);
                float v  = d + m - LOG2F(ss);
                diag = left;                         // next row's diag = old prev[r]
                up   = v;                            // next row's up   = this value
                prev[r] = v;
            }
            bottom = up;                             // row 6t+6, col j
        }
        float sh = __shfl_up(bottom, 1, 64);
        up_diag = up_cur;
        up_cur  = (t == 0) ? KINF2 : sh;
    }
    // R[384][384] = lane 63's bottom after its last step (s = 447)
    if (t == 63) out[b] = bottom * LN2;
}

// ---------------------------------------------------------------------------
extern "C" void kernel_launch(void* const* d_in, const int* in_sizes, int n_in,
                              void* d_out, int out_size, void* d_ws, size_t ws_size,
                              hipStream_t stream) {
    (void)in_sizes; (void)n_in; (void)out_size; (void)ws_size;
    const float* a = (const float*)d_in[0];
    const float* b = (const float*)d_in[1];
    float* out = (float*)d_out;

    // workspace layout (all fp32): anorm | bnorm | D   -> 75,890,688 bytes
    float* anorm = (float*)d_ws;
    float* bnorm = anorm + (long)BATCH * SEQN;
    float* Dmat  = bnorm + (long)BATCH * SEQM;

    // 98304 rows total, 4 rows (waves) per 256-thread block -> 24576 blocks
    norms_kernel<<<dim3(24576), dim3(256), 0, stream>>>(a, b, anorm, bnorm);
    gemm_kernel<<<dim3(SEQM / 64, SEQN / 64, BATCH), dim3(256), 0, stream>>>(
        a, b, anorm, bnorm, Dmat);
    dtw_kernel<<<dim3(BATCH), dim3(64), 0, stream>>>(Dmat, out);
}

// Round 5
// 328.133 us; speedup vs baseline: 1.5060x; 1.3020x over previous
//
#include <hip/hip_runtime.h>
#include <stdint.h>

// Problem constants (fixed by the reference setup_inputs)
#define BATCH 128
#define SEQN  384
#define SEQM  384
#define DIM   128
#define KINF   1000000.0f                 // reference pseudo-infinity (nat units)
#define LOG2E  1.4426950408889634f
#define LN2    0.6931471805599453f
#define KINF2  (KINF * LOG2E)             // pseudo-infinity in base-2-scaled units

// hardware base-2 transcendentals (v_exp_f32 / v_log_f32)
#define EXP2F(x) __builtin_amdgcn_exp2f(x)
#define LOG2F(x) __builtin_amdgcn_logf(x)

typedef __attribute__((ext_vector_type(8))) short bf16x8;   // 8 bf16 = 4 VGPRs (MFMA A/B frag)
typedef __attribute__((ext_vector_type(4))) float f32x4;    // MFMA C/D frag

__device__ __forceinline__ unsigned short bf16_rne(float x) {
    uint32_t u = __float_as_uint(x);
    u += 0x7FFFu + ((u >> 16) & 1u);
    return (unsigned short)(u >> 16);
}
__device__ __forceinline__ uint32_t bf16_pair(float x, float y) {
    uint32_t ux = __float_as_uint(x); ux += 0x7FFFu + ((ux >> 16) & 1u);
    uint32_t uy = __float_as_uint(y); uy += 0x7FFFu + ((uy >> 16) & 1u);
    return (ux >> 16) | (uy & 0xFFFF0000u);
}
__device__ __forceinline__ float bf16_to_f32(unsigned short v) {
    return __uint_as_float(((uint32_t)v) << 16);
}

// ---------------------------------------------------------------------------
// Kernel 1: prep.  One wave per row: squared-norm (shuffle reduce) AND a
// bf16 copy of the row (so the GEMM does zero conversions).
// ---------------------------------------------------------------------------
__global__ __launch_bounds__(256) void prep_kernel(
        const float* __restrict__ a, const float* __restrict__ b,
        unsigned short* __restrict__ a16, unsigned short* __restrict__ b16,
        float* __restrict__ anorm, float* __restrict__ bnorm) {
    int wave = threadIdx.x >> 6;
    int lane = threadIdx.x & 63;
    long row = (long)blockIdx.x * 4 + wave;          // 0 .. 98303
    const long total = (long)BATCH * SEQN;           // 49152
    const float* src; unsigned short* d16; float* dst; long r;
    if (row < total) { src = a; d16 = a16; dst = anorm; r = row; }
    else             { src = b; d16 = b16; dst = bnorm; r = row - total; }
    float2 v = ((const float2*)(src + r * DIM))[lane];
    ((uint32_t*)(d16 + r * DIM))[lane] = bf16_pair(v.x, v.y);
    float s = v.x * v.x + v.y * v.y;
    #pragma unroll
    for (int off = 32; off > 0; off >>= 1) s += __shfl_down(s, off, 64);
    if (lane == 0) dst[r] = s;
}

// ---------------------------------------------------------------------------
// Kernel 2: batched D = (anorm[i] + bnorm[j] - 2 * a.b) * LOG2E, bf16 MFMA
// on precast bf16 inputs (no conversions in the K-loop), output bf16 (RNE).
// ---------------------------------------------------------------------------
__global__ __launch_bounds__(256) void gemm_kernel(
        const unsigned short* __restrict__ a16, const unsigned short* __restrict__ b16,
        const float* __restrict__ anorm, const float* __restrict__ bnorm,
        unsigned short* __restrict__ Dmat) {
    const int batch = blockIdx.z;
    const int it = blockIdx.y, jt = blockIdx.x;
    const int wave = threadIdx.x >> 6, lane = threadIdx.x & 63;
    const int wi = wave >> 1, wj = wave & 1;
    const int i0 = it * 64 + wi * 32;
    const int j0 = jt * 64 + wj * 32;
    const int l16 = lane & 15, quad = lane >> 4;

    const unsigned short* abase = a16 + ((long)batch * SEQN + i0 + l16) * DIM + quad * 8;
    const unsigned short* bbase = b16 + ((long)batch * SEQM + j0 + l16) * DIM + quad * 8;

    f32x4 acc[2][2] = {};
    #pragma unroll
    for (int kk = 0; kk < 4; kk++) {                 // K = 4 * 32
        bf16x8 af[2], bfr[2];
        #pragma unroll
        for (int s = 0; s < 2; s++) {
            af[s]  = *(const bf16x8*)(abase + (long)s * 16 * DIM + kk * 32);
            bfr[s] = *(const bf16x8*)(bbase + (long)s * 16 * DIM + kk * 32);
        }
        #pragma unroll
        for (int si = 0; si < 2; si++)
            #pragma unroll
            for (int sj = 0; sj < 2; sj++)
                acc[si][sj] = __builtin_amdgcn_mfma_f32_16x16x32_bf16(
                                  af[si], bfr[sj], acc[si][sj], 0, 0, 0);
    }

    #pragma unroll
    for (int si = 0; si < 2; si++) {
        #pragma unroll
        for (int sj = 0; sj < 2; sj++) {
            int j = j0 + sj * 16 + l16;
            float bn = bnorm[(long)batch * SEQM + j];
            #pragma unroll
            for (int r = 0; r < 4; r++) {
                int i = i0 + si * 16 + quad * 4 + r;
                float v = (anorm[(long)batch * SEQN + i] + bn - 2.0f * acc[si][sj][r]) * LOG2E;
                Dmat[((long)batch * SEQN + i) * SEQM + j] = bf16_rne(v);
            }
        }
    }
}

// ---------------------------------------------------------------------------
// Kernel 3: soft-DTW DP.  One wave per batch, skew-2 lane pipeline: lane t
// owns rows 6t+1..6t+6, at step s computes column j = s - 2t.  Cross-lane
// boundary values travel via one __shfl_up per step with 2 steps of slack.
// INF-flow: out-of-range columns read clamped D + KINF2 (added at refill,
// off the critical path); invalid cells then compute pseudo-INF values that
// behave exactly like the reference's 1e6 boundary (exp2 underflow).  No
// per-cell masking; exactly 510 phases so lane 63's last write is R[N][M].
// D FIFO: dslot[q][r], statically indexed (register-resident), refilled one
// column per phase, 4 columns of slack vs consumption (covers HBM latency).
// ---------------------------------------------------------------------------
__global__ __launch_bounds__(64) void dtw_kernel(
        const unsigned short* __restrict__ D16, float* __restrict__ out) {
    const int b = blockIdx.x;
    const int t = threadIdx.x;                       // lane 0..63
    const unsigned short* __restrict__ dbase =
        D16 + ((long)b * SEQN + t * 6) * SEQM;

    float prev[6];
    #pragma unroll
    for (int r = 0; r < 6; r++) prev[r] = KINF2;

    // initial fill: slot q holds column (q - 2t) = first consumption's j-1
    float dslot[4][6];
    #pragma unroll
    for (int q = 0; q < 4; q++) {
        int c0 = q - 2 * t;                          // <= 3, may be negative
        int cc = c0 < 0 ? 0 : c0;                    // clamp low (always <384)
        float dadd = ((unsigned)c0 < (unsigned)SEQM) ? 0.0f : KINF2;
        #pragma unroll
        for (int r = 0; r < 6; r++)
            dslot[q][r] = bf16_to_f32(dbase[(long)r * SEQM + cc]) + dadd;
    }

    // shuffle pipeline: a_m1(s) = neighbor bottom from step s;
    // up_cur used at step s+1 = neighbor bottom col j; up_diag = col j-1.
    float up_cur = KINF2, up_diag = KINF2, a_m1 = KINF2;
    float lane0_diag = 0.0f;                         // R[0][0]; KINF2 afterwards
    const bool isl0 = (t == 0);
    int j0 = 1 - 2 * t;

#define PHASE(Q)                                                            \
    {                                                                       \
        const int j = j0 + (Q);                                             \
        float up   = isl0 ? KINF2      : up_cur;                            \
        float diag = isl0 ? lane0_diag : up_diag;                           \
        _Pragma("unroll")                                                   \
        for (int r = 0; r < 6; r++) {                                       \
            float left = prev[r];                                           \
            float pm = fminf(diag, left), pM = fmaxf(diag, left);           \
            float m  = fminf(pm, up),     o2 = fmaxf(pm, up);               \
            float e1 = EXP2F(m - pM), e2 = EXP2F(m - o2);                   \
            float v  = (dslot[Q][r] + m) - LOG2F(e1 + e2 + 1.0f);           \
            diag = left; up = v; prev[r] = v;                               \
        }                                                                   \
        int cn = j + 3;                              /* consumed at j+4 */  \
        int cc = cn < 0 ? 0 : (cn > (SEQM - 1) ? (SEQM - 1) : cn);          \
        float dadd = ((unsigned)cn < (unsigned)SEQM) ? 0.0f : KINF2;        \
        _Pragma("unroll")                                                   \
        for (int r = 0; r < 6; r++)                                         \
            dslot[Q][r] = bf16_to_f32(dbase[(long)r * SEQM + cc]) + dadd;   \
        float bottom = prev[5];                                             \
        up_diag = up_cur; up_cur = a_m1;                                    \
        a_m1 = __shfl_up(bottom, 1, 64);                                    \
        lane0_diag = KINF2;                                                 \
    }

    for (int blk = 0; blk < 127; blk++) {            // 508 phases
        PHASE(0) PHASE(1) PHASE(2) PHASE(3)
        j0 += 4;
    }
    PHASE(0) PHASE(1)                                // phases 509, 510:
                                                     // lane 63 ends at j=384
#undef PHASE

    // R[384][384] = lane 63's row-384 value at column 384 (its final phase)
    if (t == 63) out[b] = prev[5] * LN2;
}

// ---------------------------------------------------------------------------
extern "C" void kernel_launch(void* const* d_in, const int* in_sizes, int n_in,
                              void* d_out, int out_size, void* d_ws, size_t ws_size,
                              hipStream_t stream) {
    (void)in_sizes; (void)n_in; (void)out_size; (void)ws_size;
    const float* a = (const float*)d_in[0];
    const float* b = (const float*)d_in[1];
    float* out = (float*)d_out;

    // ws layout: D16 | a16 | b16 | anorm | bnorm  -> 63,307,776 bytes total
    // (round-1/3 proved >= 75.9 MB available; every access is in-region now)
    unsigned short* Dmat = (unsigned short*)d_ws;                 // 18,874,368 elems
    unsigned short* a16  = Dmat + (long)BATCH * SEQN * SEQM;      //  6,291,456 elems
    unsigned short* b16  = a16  + (long)BATCH * SEQN * DIM;       //  6,291,456 elems
    float* anorm = (float*)(b16 + (long)BATCH * SEQM * DIM);
    float* bnorm = anorm + (long)BATCH * SEQN;

    prep_kernel<<<dim3(24576), dim3(256), 0, stream>>>(a, b, a16, b16, anorm, bnorm);
    gemm_kernel<<<dim3(SEQM / 64, SEQN / 64, BATCH), dim3(256), 0, stream>>>(
        a16, b16, anorm, bnorm, Dmat);
    dtw_kernel<<<dim3(BATCH), dim3(64), 0, stream>>>(Dmat, out);
}

// Round 6
// 256.561 us; speedup vs baseline: 1.9262x; 1.2790x over previous
//
#include <hip/hip_runtime.h>
#include <stdint.h>

// Problem constants (fixed by the reference setup_inputs)
#define BATCH 128
#define SEQN  384
#define SEQM  384
#define DIM   128
#define KINF   1000000.0f                 // reference pseudo-infinity (nat units)
#define LOG2E  1.4426950408889634f
#define LN2    0.6931471805599453f
#define KINF2  (KINF * LOG2E)             // pseudo-infinity in base-2-scaled units

// hardware base-2 transcendentals (v_exp_f32 / v_log_f32)
#define EXP2F(x) __builtin_amdgcn_exp2f(x)
#define LOG2F(x) __builtin_amdgcn_logf(x)

typedef __attribute__((ext_vector_type(8))) short bf16x8;   // 8 bf16 = 4 VGPRs (MFMA A/B frag)
typedef __attribute__((ext_vector_type(4))) float f32x4;    // MFMA C/D frag

__device__ __forceinline__ unsigned short bf16_rne(float x) {
    uint32_t u = __float_as_uint(x);
    u += 0x7FFFu + ((u >> 16) & 1u);
    return (unsigned short)(u >> 16);
}
__device__ __forceinline__ uint32_t bf16_pair(float x, float y) {
    uint32_t ux = __float_as_uint(x); ux += 0x7FFFu + ((ux >> 16) & 1u);
    uint32_t uy = __float_as_uint(y); uy += 0x7FFFu + ((uy >> 16) & 1u);
    return (ux >> 16) | (uy & 0xFFFF0000u);
}

// ---------------------------------------------------------------------------
// Kernel 1: prep.  One wave per row: squared-norm (shuffle reduce) AND a
// bf16 copy of the row (so the GEMM does zero conversions).
// ---------------------------------------------------------------------------
__global__ __launch_bounds__(256) void prep_kernel(
        const float* __restrict__ a, const float* __restrict__ b,
        unsigned short* __restrict__ a16, unsigned short* __restrict__ b16,
        float* __restrict__ anorm, float* __restrict__ bnorm) {
    int wave = threadIdx.x >> 6;
    int lane = threadIdx.x & 63;
    long row = (long)blockIdx.x * 4 + wave;          // 0 .. 98303
    const long total = (long)BATCH * SEQN;           // 49152
    const float* src; unsigned short* d16; float* dst; long r;
    if (row < total) { src = a; d16 = a16; dst = anorm; r = row; }
    else             { src = b; d16 = b16; dst = bnorm; r = row - total; }
    float2 v = ((const float2*)(src + r * DIM))[lane];
    ((uint32_t*)(d16 + r * DIM))[lane] = bf16_pair(v.x, v.y);
    float s = v.x * v.x + v.y * v.y;
    #pragma unroll
    for (int off = 32; off > 0; off >>= 1) s += __shfl_down(s, off, 64);
    if (lane == 0) dst[r] = s;
}

// ---------------------------------------------------------------------------
// Kernel 2: batched tile GEMM, D = (rn[i] + cn[j] - 2 * r.c) * LOG2E, bf16
// MFMA on precast bf16 inputs, output bf16 (RNE).  Called with rows=b,
// cols=a so it writes Dt[batch][b_row][a_row] (transposed D for the DP).
// ---------------------------------------------------------------------------
__global__ __launch_bounds__(256) void gemm_kernel(
        const unsigned short* __restrict__ rows16, const unsigned short* __restrict__ cols16,
        const float* __restrict__ rnorm, const float* __restrict__ cnorm,
        unsigned short* __restrict__ Dmat) {
    const int batch = blockIdx.z;
    const int it = blockIdx.y, jt = blockIdx.x;
    const int wave = threadIdx.x >> 6, lane = threadIdx.x & 63;
    const int wi = wave >> 1, wj = wave & 1;
    const int i0 = it * 64 + wi * 32;
    const int j0 = jt * 64 + wj * 32;
    const int l16 = lane & 15, quad = lane >> 4;

    const unsigned short* abase = rows16 + ((long)batch * SEQM + i0 + l16) * DIM + quad * 8;
    const unsigned short* bbase = cols16 + ((long)batch * SEQN + j0 + l16) * DIM + quad * 8;

    f32x4 acc[2][2] = {};
    #pragma unroll
    for (int kk = 0; kk < 4; kk++) {                 // K = 4 * 32
        bf16x8 af[2], bfr[2];
        #pragma unroll
        for (int s = 0; s < 2; s++) {
            af[s]  = *(const bf16x8*)(abase + (long)s * 16 * DIM + kk * 32);
            bfr[s] = *(const bf16x8*)(bbase + (long)s * 16 * DIM + kk * 32);
        }
        #pragma unroll
        for (int si = 0; si < 2; si++)
            #pragma unroll
            for (int sj = 0; sj < 2; sj++)
                acc[si][sj] = __builtin_amdgcn_mfma_f32_16x16x32_bf16(
                                  af[si], bfr[sj], acc[si][sj], 0, 0, 0);
    }

    #pragma unroll
    for (int si = 0; si < 2; si++) {
        #pragma unroll
        for (int sj = 0; sj < 2; sj++) {
            int j = j0 + sj * 16 + l16;
            float bn = cnorm[(long)batch * SEQN + j];
            #pragma unroll
            for (int r = 0; r < 4; r++) {
                int i = i0 + si * 16 + quad * 4 + r;
                float v = (rnorm[(long)batch * SEQM + i] + bn - 2.0f * acc[si][sj][r]) * LOG2E;
                Dmat[((long)batch * SEQM + i) * SEQN + j] = bf16_rne(v);
            }
        }
    }
}

// ---------------------------------------------------------------------------
// Kernel 3: soft-DTW DP.  One wave per batch, skew-2 lane pipeline: lane t
// owns rows 6t+1..6t+6, at step s computes column j = s - 2t.  INF-flow
// boundary handling (out-of-range columns get +KINF2 at consume time).
// D is transposed (Dt[b][col][row]) so a lane's 6 values for one column are
// ONE 12-byte global load, kept RAW in a 4-deep register FIFO; conversion
// happens at consumption 4 phases later, so s_waitcnt vmcnt(3) hides the
// full memory latency.  Softmin restructured: pair-softmin of (diag,left)
// precomputed off-chain (prev-phase data only); the up-dependent chain is
// sub -> min -> exp2 -> fma/cndmask -> log2 -> sub (~44 cyc/cell).
// ---------------------------------------------------------------------------
__global__ __launch_bounds__(64) void dtw_kernel(
        const unsigned short* __restrict__ Dt, float* __restrict__ out) {
    const int b = blockIdx.x;
    const int t = threadIdx.x;                       // lane 0..63
    // lane base: column-major Dt, rows 6t..6t+5 contiguous (12 B, 4-aligned)
    const unsigned short* __restrict__ dtb =
        Dt + (long)b * SEQM * SEQN + 6 * t;

    float prev[6];
    #pragma unroll
    for (int r = 0; r < 6; r++) prev[r] = KINF2;

    // raw D FIFO: slot q holds D column (q - 2t + 4k) bits; dadd = validity
    uint3 dslot[4];
    float dadd[4];
    #pragma unroll
    for (int q = 0; q < 4; q++) {
        int c0 = q - 2 * t;                          // <= 3, may be negative
        int cc = c0 < 0 ? 0 : c0;                    // clamp (always < 384)
        dslot[q] = *(const uint3*)(dtb + (long)cc * SEQN);
        dadd[q]  = ((unsigned)c0 < (unsigned)SEQM) ? 0.0f : KINF2;
    }

    // shuffle pipeline (2 phases of slack, proven in r5)
    float up_cur = KINF2, up_diag = KINF2, a_m1 = KINF2;
    float lane0_diag = 0.0f;                         // R[0][0]; KINF2 afterwards
    const bool isl0 = (t == 0);
    int j0 = 1 - 2 * t;

#define PHASE(Q)                                                            \
    {                                                                       \
        const int j = j0 + (Q);                                             \
        /* unpack current slot (its load issued 4 phases ago) */            \
        uint3 w = dslot[Q];                                                 \
        float da = dadd[Q];                                                 \
        float d[6];                                                         \
        d[0] = __uint_as_float(w.x << 16)          + da;                    \
        d[1] = __uint_as_float(w.x & 0xFFFF0000u)  + da;                    \
        d[2] = __uint_as_float(w.y << 16)          + da;                    \
        d[3] = __uint_as_float(w.y & 0xFFFF0000u)  + da;                    \
        d[4] = __uint_as_float(w.z << 16)          + da;                    \
        d[5] = __uint_as_float(w.z & 0xFFFF0000u)  + da;                    \
        /* refill slot Q for column j+4 (D col j+3) -- raw, no wait */      \
        {                                                                   \
            int cn = j + 3;                                                 \
            int cc = cn < 0 ? 0 : (cn > (SEQM - 1) ? (SEQM - 1) : cn);      \
            dslot[Q] = *(const uint3*)(dtb + (long)cc * SEQN);              \
            dadd[Q]  = ((unsigned)cn < (unsigned)SEQM) ? 0.0f : KINF2;      \
        }                                                                   \
        /* off-chain precompute from previous-phase state */                \
        float dg = isl0 ? lane0_diag : up_diag;                             \
        float up = isl0 ? KINF2      : up_cur;                              \
        float pm[6], Sp[6], dpm[6];                                         \
        _Pragma("unroll")                                                   \
        for (int r = 0; r < 6; r++) {                                       \
            float dgr = (r == 0) ? dg : prev[r - 1];                        \
            float lf  = prev[r];                                            \
            float mn = fminf(dgr, lf), mx = fmaxf(dgr, lf);                 \
            pm[r]  = mn;                                                    \
            Sp[r]  = EXP2F(mn - mx) + 1.0f;                                 \
            dpm[r] = d[r] + mn;                                             \
        }                                                                   \
        /* the serial chain */                                              \
        _Pragma("unroll")                                                   \
        for (int r = 0; r < 6; r++) {                                       \
            float delta = up - pm[r];                                       \
            float x  = fminf(delta, -delta);         /* -|delta| */         \
            float fm = fminf(delta, 0.0f);                                  \
            float e  = EXP2F(x);                                            \
            float tn = __builtin_fmaf(e, Sp[r], 1.0f);                      \
            float tp = Sp[r] + e;                                           \
            float tot = (delta < 0.0f) ? tn : tp;                           \
            float v = (dpm[r] + fm) - LOG2F(tot);                           \
            prev[r] = v; up = v;                                            \
        }                                                                   \
        float bottom = prev[5];                                             \
        up_diag = up_cur; up_cur = a_m1;                                    \
        a_m1 = __shfl_up(bottom, 1, 64);                                    \
        lane0_diag = KINF2;                                                 \
    }

    for (int blk = 0; blk < 127; blk++) {            // 508 phases
        PHASE(0) PHASE(1) PHASE(2) PHASE(3)
        j0 += 4;
    }
    PHASE(0) PHASE(1)                                // phases 509, 510:
                                                     // lane 63 ends at j=384
#undef PHASE

    // R[384][384] = lane 63's row-384 value at column 384 (its final phase)
    if (t == 63) out[b] = prev[5] * LN2;
}

// ---------------------------------------------------------------------------
extern "C" void kernel_launch(void* const* d_in, const int* in_sizes, int n_in,
                              void* d_out, int out_size, void* d_ws, size_t ws_size,
                              hipStream_t stream) {
    (void)in_sizes; (void)n_in; (void)out_size; (void)ws_size;
    const float* a = (const float*)d_in[0];
    const float* b = (const float*)d_in[1];
    float* out = (float*)d_out;

    // ws layout: Dt | a16 | b16 | anorm | bnorm  -> 63,307,776 bytes total
    unsigned short* Dmat = (unsigned short*)d_ws;                 // 18,874,368 elems
    unsigned short* a16  = Dmat + (long)BATCH * SEQN * SEQM;      //  6,291,456 elems
    unsigned short* b16  = a16  + (long)BATCH * SEQN * DIM;       //  6,291,456 elems
    float* anorm = (float*)(b16 + (long)BATCH * SEQM * DIM);
    float* bnorm = anorm + (long)BATCH * SEQN;

    prep_kernel<<<dim3(24576), dim3(256), 0, stream>>>(a, b, a16, b16, anorm, bnorm);
    // rows = b (Dt row index = DP column), cols = a  ->  Dt[b][j][i]
    gemm_kernel<<<dim3(SEQN / 64, SEQM / 64, BATCH), dim3(256), 0, stream>>>(
        b16, a16, bnorm, anorm, Dmat);
    dtw_kernel<<<dim3(BATCH), dim3(64), 0, stream>>>(Dmat, out);
}

// Round 7
// 240.057 us; speedup vs baseline: 2.0586x; 1.0688x over previous
//
#include <hip/hip_runtime.h>
#include <stdint.h>

// Problem constants (fixed by the reference setup_inputs)
#define BATCH 128
#define SEQN  384
#define SEQM  384
#define DIM   128
#define KINF   1000000.0f                 // reference pseudo-infinity (nat units)
#define LOG2E  1.4426950408889634f
#define LN2    0.6931471805599453f
#define KINF2  (KINF * LOG2E)             // pseudo-infinity in base-2-scaled units

// hardware base-2 transcendentals (v_exp_f32 / v_log_f32)
#define EXP2F(x) __builtin_amdgcn_exp2f(x)
#define LOG2F(x) __builtin_amdgcn_logf(x)

typedef __attribute__((ext_vector_type(8))) short bf16x8;   // 8 bf16 = 4 VGPRs (MFMA A/B frag)
typedef __attribute__((ext_vector_type(4))) float f32x4;    // MFMA C/D frag

__device__ __forceinline__ unsigned short bf16_rne(float x) {
    uint32_t u = __float_as_uint(x);
    u += 0x7FFFu + ((u >> 16) & 1u);
    return (unsigned short)(u >> 16);
}
__device__ __forceinline__ uint32_t bf16_pair(float x, float y) {
    uint32_t ux = __float_as_uint(x); ux += 0x7FFFu + ((ux >> 16) & 1u);
    uint32_t uy = __float_as_uint(y); uy += 0x7FFFu + ((uy >> 16) & 1u);
    return (ux >> 16) | (uy & 0xFFFF0000u);
}

// ---------------------------------------------------------------------------
// Kernel 1: prep.  One wave per row: squared-norm (shuffle reduce) AND a
// bf16 copy of the row (so the GEMM does zero conversions).
// ---------------------------------------------------------------------------
__global__ __launch_bounds__(256) void prep_kernel(
        const float* __restrict__ a, const float* __restrict__ b,
        unsigned short* __restrict__ a16, unsigned short* __restrict__ b16,
        float* __restrict__ anorm, float* __restrict__ bnorm) {
    int wave = threadIdx.x >> 6;
    int lane = threadIdx.x & 63;
    long row = (long)blockIdx.x * 4 + wave;          // 0 .. 98303
    const long total = (long)BATCH * SEQN;           // 49152
    const float* src; unsigned short* d16; float* dst; long r;
    if (row < total) { src = a; d16 = a16; dst = anorm; r = row; }
    else             { src = b; d16 = b16; dst = bnorm; r = row - total; }
    float2 v = ((const float2*)(src + r * DIM))[lane];
    ((uint32_t*)(d16 + r * DIM))[lane] = bf16_pair(v.x, v.y);
    float s = v.x * v.x + v.y * v.y;
    #pragma unroll
    for (int off = 32; off > 0; off >>= 1) s += __shfl_down(s, off, 64);
    if (lane == 0) dst[r] = s;
}

// ---------------------------------------------------------------------------
// Kernel 2: batched tile GEMM with LDS staging.
// Dt[b][j][i] = (anorm[i] + bnorm[j] - 2 * a_i.b_j) * LOG2E, stored bf16.
// 128x128 tile per 256-thread block, K=128 in one pass, 64 KB LDS.
// Staging is fully coalesced (tiles are contiguous 32 KB global regions).
// LDS rows are XOR-swizzled in 8-elem groups (grp ^ (row&15)) so the MFMA
// fragment reads (16 lanes @ 256 B row stride) spread across bank groups.
// A-operand = a-rows (i) so C/D rows (quad*4+reg) = i -> each lane's 4
// outputs are contiguous in Dt -> ushort4 stores.
// ---------------------------------------------------------------------------
__global__ __launch_bounds__(256) void gemm_kernel(
        const unsigned short* __restrict__ a16, const unsigned short* __restrict__ b16,
        const float* __restrict__ anorm, const float* __restrict__ bnorm,
        unsigned short* __restrict__ Dt) {
    __shared__ unsigned short lds[2][128][128];      // [0]=A(i-rows) [1]=B(j-rows), 64 KB
    const int batch = blockIdx.z;
    const int i0 = blockIdx.x * 128;                 // a-row tile
    const int j0 = blockIdx.y * 128;                 // b-row tile
    const int t  = threadIdx.x;

    const unsigned short* __restrict__ asrc = a16 + ((long)batch * SEQN + i0) * DIM;
    const unsigned short* __restrict__ bsrc = b16 + ((long)batch * SEQM + j0) * DIM;

    // stage both 32 KB tiles: 8 passes x 256 threads x 16 B, coalesced
    #pragma unroll
    for (int p = 0; p < 8; p++) {
        int e   = p * 2048 + t * 8;                  // element index in tile
        int row = e >> 7;                            // 0..127
        int grp = (e >> 3) & 15;                     // 8-elem group 0..15
        uint4 va = *(const uint4*)(asrc + e);
        uint4 vb = *(const uint4*)(bsrc + e);
        int sw = ((grp ^ (row & 15)) * 8);           // swizzled elem offset
        *(uint4*)&lds[0][row][sw] = va;
        *(uint4*)&lds[1][row][sw] = vb;
    }
    __syncthreads();

    const int wave = t >> 6, lane = t & 63;
    const int iq = (wave & 1) * 64;                  // wave quadrant
    const int jq = (wave >> 1) * 64;
    const int l16 = lane & 15, q = lane >> 4;

    f32x4 acc[4][4] = {};                            // [si (i-dir)][sj (j-dir)]
    #pragma unroll
    for (int kk = 0; kk < 4; kk++) {                 // K = 4 * 32
        bf16x8 af[4], bfr[4];
        #pragma unroll
        for (int s = 0; s < 4; s++) {
            int arow = iq + s * 16 + l16;
            af[s]  = *(const bf16x8*)&lds[0][arow][((kk * 4 + q) ^ (arow & 15)) * 8];
            int brow = jq + s * 16 + l16;
            bfr[s] = *(const bf16x8*)&lds[1][brow][((kk * 4 + q) ^ (brow & 15)) * 8];
        }
        #pragma unroll
        for (int si = 0; si < 4; si++)
            #pragma unroll
            for (int sj = 0; sj < 4; sj++)
                acc[si][sj] = __builtin_amdgcn_mfma_f32_16x16x32_bf16(
                                  af[si], bfr[sj], acc[si][sj], 0, 0, 0);
    }

    // epilogue: lane holds col j = j0+jq+sj*16+l16, rows i = i0+iq+si*16+q*4+r
    #pragma unroll
    for (int sj = 0; sj < 4; sj++) {
        int j = j0 + jq + sj * 16 + l16;
        float bn = bnorm[(long)batch * SEQM + j];
        unsigned short* drow = Dt + ((long)batch * SEQM + j) * SEQN;
        #pragma unroll
        for (int si = 0; si < 4; si++) {
            int i = i0 + iq + si * 16 + q * 4;
            float4 an = *(const float4*)&anorm[(long)batch * SEQN + i];
            ushort4 pack;
            pack.x = bf16_rne((an.x + bn - 2.0f * acc[si][sj][0]) * LOG2E);
            pack.y = bf16_rne((an.y + bn - 2.0f * acc[si][sj][1]) * LOG2E);
            pack.z = bf16_rne((an.z + bn - 2.0f * acc[si][sj][2]) * LOG2E);
            pack.w = bf16_rne((an.w + bn - 2.0f * acc[si][sj][3]) * LOG2E);
            *(ushort4*)(drow + i) = pack;
        }
    }
}

// ---------------------------------------------------------------------------
// Kernel 3: soft-DTW DP (unchanged from round 6 — passing, 129.5 us).
// ---------------------------------------------------------------------------
__global__ __launch_bounds__(64) void dtw_kernel(
        const unsigned short* __restrict__ Dt, float* __restrict__ out) {
    const int b = blockIdx.x;
    const int t = threadIdx.x;                       // lane 0..63
    const unsigned short* __restrict__ dtb =
        Dt + (long)b * SEQM * SEQN + 6 * t;

    float prev[6];
    #pragma unroll
    for (int r = 0; r < 6; r++) prev[r] = KINF2;

    uint3 dslot[4];
    float dadd[4];
    #pragma unroll
    for (int q = 0; q < 4; q++) {
        int c0 = q - 2 * t;
        int cc = c0 < 0 ? 0 : c0;
        dslot[q] = *(const uint3*)(dtb + (long)cc * SEQN);
        dadd[q]  = ((unsigned)c0 < (unsigned)SEQM) ? 0.0f : KINF2;
    }

    float up_cur = KINF2, up_diag = KINF2, a_m1 = KINF2;
    float lane0_diag = 0.0f;
    const bool isl0 = (t == 0);
    int j0 = 1 - 2 * t;

#define PHASE(Q)                                                            \
    {                                                                       \
        const int j = j0 + (Q);                                             \
        uint3 w = dslot[Q];                                                 \
        float da = dadd[Q];                                                 \
        float d[6];                                                         \
        d[0] = __uint_as_float(w.x << 16)          + da;                    \
        d[1] = __uint_as_float(w.x & 0xFFFF0000u)  + da;                    \
        d[2] = __uint_as_float(w.y << 16)          + da;                    \
        d[3] = __uint_as_float(w.y & 0xFFFF0000u)  + da;                    \
        d[4] = __uint_as_float(w.z << 16)          + da;                    \
        d[5] = __uint_as_float(w.z & 0xFFFF0000u)  + da;                    \
        {                                                                   \
            int cn = j + 3;                                                 \
            int cc = cn < 0 ? 0 : (cn > (SEQM - 1) ? (SEQM - 1) : cn);      \
            dslot[Q] = *(const uint3*)(dtb + (long)cc * SEQN);              \
            dadd[Q]  = ((unsigned)cn < (unsigned)SEQM) ? 0.0f : KINF2;      \
        }                                                                   \
        float dg = isl0 ? lane0_diag : up_diag;                             \
        float up = isl0 ? KINF2      : up_cur;                              \
        float pm[6], Sp[6], dpm[6];                                         \
        _Pragma("unroll")                                                   \
        for (int r = 0; r < 6; r++) {                                       \
            float dgr = (r == 0) ? dg : prev[r - 1];                        \
            float lf  = prev[r];                                            \
            float mn = fminf(dgr, lf), mx = fmaxf(dgr, lf);                 \
            pm[r]  = mn;                                                    \
            Sp[r]  = EXP2F(mn - mx) + 1.0f;                                 \
            dpm[r] = d[r] + mn;                                             \
        }                                                                   \
        _Pragma("unroll")                                                   \
        for (int r = 0; r < 6; r++) {                                       \
            float delta = up - pm[r];                                       \
            float x  = fminf(delta, -delta);                                \
            float fm = fminf(delta, 0.0f);                                  \
            float e  = EXP2F(x);                                            \
            float tn = __builtin_fmaf(e, Sp[r], 1.0f);                      \
            float tp = Sp[r] + e;                                           \
            float tot = (delta < 0.0f) ? tn : tp;                           \
            float v = (dpm[r] + fm) - LOG2F(tot);                           \
            prev[r] = v; up = v;                                            \
        }                                                                   \
        float bottom = prev[5];                                             \
        up_diag = up_cur; up_cur = a_m1;                                    \
        a_m1 = __shfl_up(bottom, 1, 64);                                    \
        lane0_diag = KINF2;                                                 \
    }

    for (int blk = 0; blk < 127; blk++) {            // 508 phases
        PHASE(0) PHASE(1) PHASE(2) PHASE(3)
        j0 += 4;
    }
    PHASE(0) PHASE(1)                                // phases 509, 510
#undef PHASE

    if (t == 63) out[b] = prev[5] * LN2;
}

// ---------------------------------------------------------------------------
extern "C" void kernel_launch(void* const* d_in, const int* in_sizes, int n_in,
                              void* d_out, int out_size, void* d_ws, size_t ws_size,
                              hipStream_t stream) {
    (void)in_sizes; (void)n_in; (void)out_size; (void)ws_size;
    const float* a = (const float*)d_in[0];
    const float* b = (const float*)d_in[1];
    float* out = (float*)d_out;

    // ws layout: Dt | a16 | b16 | anorm | bnorm  -> 63,307,776 bytes total
    unsigned short* Dmat = (unsigned short*)d_ws;                 // 18,874,368 elems
    unsigned short* a16  = Dmat + (long)BATCH * SEQN * SEQM;      //  6,291,456 elems
    unsigned short* b16  = a16  + (long)BATCH * SEQN * DIM;       //  6,291,456 elems
    float* anorm = (float*)(b16 + (long)BATCH * SEQM * DIM);
    float* bnorm = anorm + (long)BATCH * SEQN;

    prep_kernel<<<dim3(24576), dim3(256), 0, stream>>>(a, b, a16, b16, anorm, bnorm);
    gemm_kernel<<<dim3(SEQN / 128, SEQM / 128, BATCH), dim3(256), 0, stream>>>(
        a16, b16, anorm, bnorm, Dmat);
    dtw_kernel<<<dim3(BATCH), dim3(64), 0, stream>>>(Dmat, out);
}